// Round 27
// baseline (93.443 us; speedup 1.0000x reference)
//
#include <hip/hip_runtime.h>

typedef unsigned short u16;
typedef __attribute__((ext_vector_type(4))) float f32x4;
typedef __attribute__((ext_vector_type(8))) __bf16 bf16x8;

__device__ __forceinline__ u16 f2bf(float f) {
  unsigned u = __builtin_bit_cast(unsigned, f);
  u = u + 0x7fffu + ((u >> 16) & 1u);
  return (u16)(u >> 16);
}

__device__ __forceinline__ void load_lds16(const void* g, void* l) {
  __builtin_amdgcn_global_load_lds((__attribute__((address_space(1))) void*)g,
                                   (__attribute__((address_space(3))) void*)l,
                                   16, 0, 0);
}

__device__ __forceinline__ f32x4 MF(bf16x8 a, bf16x8 b, f32x4 c) {
  return __builtin_amdgcn_mfma_f32_16x16x32_bf16(a, b, c, 0, 0, 0);
}

// GEMM-tile layout: buf[(row>>7)*(K/64) + (col>>6)][row&127][col&63], 16KB tiles.
// Each GEMM K-stage then loads ONE contiguous block per operand (r26-proven mechanism).
__device__ __forceinline__ size_t gtile_off(int row, int col, int ktiles) {
  return (size_t)((row >> 7) * ktiles + (col >> 6)) * 8192 + (row & 127) * 64 + (col & 63);
}

// Upstream-of-GEMM1 preprocessing (outputs in GEMM-tile layout):
//  blocks    0..8191: cast x (f32 -> bf16) -> Xb tiled [8192 x 1024]
//  blocks 8192..9215: cast inp_w -> Wb tiled [1024 x 1024]
__global__ __launch_bounds__(256) void prep_pre(const float* __restrict__ x,
                                                const float* __restrict__ inp_w,
                                                u16* __restrict__ Xb,
                                                u16* __restrict__ Wb) {
  const int bx = blockIdx.x, tid = threadIdx.x;
  const float* src; u16* dst; int i;
  if (bx < 8192) { src = x;     dst = Xb; i = bx * 256 + tid; }
  else           { src = inp_w; dst = Wb; i = (bx - 8192) * 256 + tid; }
  const float4 v = ((const float4*)src)[i];
  ushort4 o;
  o.x = f2bf(v.x); o.y = f2bf(v.y); o.z = f2bf(v.z); o.w = f2bf(v.w);
  const int row = i >> 8, col = (i & 255) * 4;   // lda = 1024 for both
  *(ushort4*)(dst + gtile_off(row, col, 16)) = o;
}

// Prep branches not needed by GEMM1, run as extra blocks inside GEMM1's launch:
//  ex    0..1023: cast out_w -> OWb tiled
//  ex 1024..1039: per-head cumsum of weight -> normB
//  ex 1040..1295: build Toeplitz operand V[h][t'][j] = (t'>=j)?w[h][t'-j]:0
__device__ void prep_post_block(int ex, int tid,
                                const float* __restrict__ out_w,
                                const float* __restrict__ weight,
                                u16* __restrict__ OWb,
                                float* __restrict__ normB,
                                u16* __restrict__ V) {
  if (ex < 1024) {
    const int i = ex * 256 + tid;
    const float4 v = ((const float4*)out_w)[i];
    ushort4 o;
    o.x = f2bf(v.x); o.y = f2bf(v.y); o.z = f2bf(v.z); o.w = f2bf(v.w);
    const int row = i >> 8, col = (i & 255) * 4;
    *(ushort4*)(OWb + gtile_off(row, col, 16)) = o;
    return;
  }
  if (ex < 1040) {
    const int h = ex - 1024;
    __shared__ float ts[256];
    float v[8];
    const float* src = weight + h * 2048 + tid * 8;
    float s = 0.f;
#pragma unroll
    for (int j = 0; j < 8; ++j) v[j] = src[j];
#pragma unroll
    for (int j = 0; j < 8; ++j) { s += v[j]; v[j] = s; }
    ts[tid] = s;
    __syncthreads();
    float xx = s;
#pragma unroll
    for (int d = 1; d < 256; d <<= 1) {
      float y = (tid >= d) ? ts[tid - d] : 0.f;
      __syncthreads();
      xx += y;
      ts[tid] = xx;
      __syncthreads();
    }
    const float excl = xx - s;
    float* dst = normB + h * 2048 + tid * 8;
#pragma unroll
    for (int j = 0; j < 8; ++j) dst[j] = excl + v[j];
    return;
  }
  {
    const int bb = ex - 1040;
    const int h = bb & 15, tb = bb >> 4;
    __shared__ u16 wl[2048];
#pragma unroll
    for (int j = 0; j < 8; ++j) wl[tid * 8 + j] = f2bf(weight[h * 2048 + tid * 8 + j]);
    __syncthreads();
#pragma unroll
    for (int i = 0; i < 8; ++i) {
      const int cid = i * 256 + tid;
      const int row = cid >> 4, c = cid & 15;
      const int t = tb * 128 + row;
      const int j0 = c * 8;
      unsigned v[8];
#pragma unroll
      for (int jj = 0; jj < 8; ++jj) {
        const int j = j0 + jj;
        v[jj] = (t >= j) ? (unsigned)wl[t - j] : 0u;
      }
      uint4 o;
      o.x = v[0] | (v[1] << 16); o.y = v[2] | (v[3] << 16);
      o.z = v[4] | (v[5] << 16); o.w = v[6] | (v[7] << 16);
      *(uint4*)(V + ((size_t)(h * 2048 + t)) * 128 + j0) = o;
    }
  }
}

// NT GEMM, operands in GEMM-tile layout (each stage = 2 contiguous 16KB blocks).
// BM=BN=128, BK=64, 4 waves (2x2, 64x64/wave), 2-deep LDS dbuf (64KB -> 2 blocks/CU).
// DEC=0 (GEMM1): per-XCD 8m x 8n square chunk; blocks >= 512 run prep_post overlap;
//   TILEC: C written in toep-tiled layout [h][b][stile][64d][64s].
// DEC=1 (GEMM3): sw remap, row-major f32 C.
template <bool BIAS, bool F32OUT, int DEC, bool POST, bool TILEC>
__global__ __launch_bounds__(256) void gemm_nt4(const u16* __restrict__ A,
                                                const u16* __restrict__ B,
                                                void* __restrict__ C,
                                                const float* __restrict__ bias,
                                                int K, int ldc,
                                                const float* __restrict__ out_w,
                                                const float* __restrict__ weight,
                                                u16* __restrict__ OWb,
                                                float* __restrict__ normB,
                                                u16* __restrict__ Vt) {
  const int flatAll = (int)blockIdx.x;
  if (POST && flatAll >= 512) {
    prep_post_block(flatAll - 512, threadIdx.x, out_w, weight, OWb, normB, Vt);
    return;
  }
  __shared__ __align__(16) u16 As[2][128 * 64];
  __shared__ __align__(16) u16 Bs[2][128 * 64];
  const int tid = threadIdx.x;
  const int lane = tid & 63, wv = tid >> 6;
  const int wm = wv >> 1, wn = wv & 1;
  const int l15 = lane & 15, g = lane >> 4;

  const int flat = flatAll;
  int m0, n0;
  if (DEC == 0) {
    const int xcd = flat & 7, i = flat >> 3;
    m0 = (i & 7) * 128;
    n0 = ((xcd << 3) + (i >> 3)) * 128;
  } else {
    const int sw = (flat & 7) * 64 + (flat >> 3);
    m0 = (sw >> 3) * 128;
    n0 = (sw & 7) * 128;
  }

  const int NT = K >> 6;

  auto stage = [&](int t, int bi) {
    const u16* Ablk = A + (size_t)((m0 >> 7) * NT + t) * 8192;
#pragma unroll
    for (int i = 0; i < 4; ++i) {
      const int c = i * 256 + tid;
      const int row = c >> 3, cc = c & 7;
      load_lds16(Ablk + row * 64 + ((cc ^ (row & 7)) << 3),
                 &As[bi][i * 2048 + wv * 512]);
    }
    const u16* Bblk = B + (size_t)((n0 >> 7) * NT + t) * 8192;
#pragma unroll
    for (int i = 0; i < 4; ++i) {
      const int c = i * 256 + tid;
      const int row = c >> 3, cc = c & 7;
      load_lds16(Bblk + row * 64 + ((cc ^ (row & 7)) << 3),
                 &Bs[bi][i * 2048 + wv * 512]);
    }
  };

  f32x4 acc[4][4] = {};
  stage(0, 0);
  __syncthreads();
  int cur = 0;
  for (int t = 0; t < NT; ++t) {
    if (t + 1 < NT) stage(t + 1, cur ^ 1);
#pragma unroll
    for (int kh = 0; kh < 2; ++kh) {
      bf16x8 af[4], bf[4];
#pragma unroll
      for (int mf = 0; mf < 4; ++mf) {
        const int row = wm * 64 + mf * 16 + l15;
        af[mf] = *(const bf16x8*)(&As[cur][row * 64 + ((((kh << 2) + g) ^ (row & 7)) << 3)]);
      }
#pragma unroll
      for (int nf = 0; nf < 4; ++nf) {
        const int row = wn * 64 + nf * 16 + l15;
        bf[nf] = *(const bf16x8*)(&Bs[cur][row * 64 + ((((kh << 2) + g) ^ (row & 7)) << 3)]);
      }
      __builtin_amdgcn_s_setprio(1);
#pragma unroll
      for (int mf = 0; mf < 4; ++mf)
#pragma unroll
        for (int nf = 0; nf < 4; ++nf)
          acc[mf][nf] = MF(af[mf], bf[nf], acc[mf][nf]);
      __builtin_amdgcn_s_setprio(0);
    }
    __syncthreads();
    cur ^= 1;
  }

  // D layout (m89-verified): col = lane&15, row = (lane>>4)*4 + reg
#pragma unroll
  for (int mf = 0; mf < 4; ++mf) {
#pragma unroll
    for (int r = 0; r < 4; ++r) {
      const int row = m0 + wm * 64 + mf * 16 + g * 4 + r;
      const float bb = BIAS ? bias[row] : 0.f;
#pragma unroll
      for (int nf = 0; nf < 4; ++nf) {
        const int col = n0 + wn * 64 + nf * 16 + l15;
        const float v = acc[mf][nf][r] + bb;
        if (F32OUT) {
          ((float*)C)[(size_t)row * ldc + col] = v;
        } else if (TILEC) {
          // [h][b][stile][64d][64s]: h=row>>6, d=row&63, b=col>>11, stile=(col&2047)>>6
          const size_t off = (size_t)(row >> 6) * 524288 + (size_t)(col >> 11) * 131072 +
                             (size_t)((col & 2047) >> 6) * 4096 + (row & 63) * 64 + (col & 63);
          ((u16*)C)[off] = f2bf(v);
        } else {
          ((u16*)C)[(size_t)row * ldc + col] = f2bf(v);
        }
      }
    }
  }
}

// Causal Toeplitz conv (r10 structure + r21 micro-tweaks — best measured).
// X1t tiled [h][b][stile][64d][64s] (contiguous 8KB X-stages, r26-proven);
// Y2b written in GEMM-tile layout for GEMM3 (ktile = h exactly).
__global__ __launch_bounds__(256) void toep_conv(const u16* __restrict__ X1t,
                                                 const u16* __restrict__ V,
                                                 const float* __restrict__ normB,
                                                 const float* __restrict__ biasB,
                                                 u16* __restrict__ Y2b) {
  __shared__ __align__(16) u16 As[3][128 * 64];  // 3 x 16KB
  __shared__ __align__(16) u16 Xs[3][64 * 64];   // 3 x 8KB
  const int tid = threadIdx.x;
  const int lane = tid & 63, wv = tid >> 6;
  const int l15 = lane & 15, g = lane >> 4;

  const int x = (int)blockIdx.x;
  const int h = (x & 7) + 8 * ((x >> 3) & 1);   // xcd = wgid%8 -> h%8
  const int pb = x >> 4;                        // 0..31
  const int pair = pb & 7, b = pb >> 3;         // pair 0..7, b 0..3

  const u16* Vh = V + (size_t)h * 2048 * 128;
  const u16* Xtile = X1t + (size_t)h * 524288 + (size_t)b * 131072;

#pragma unroll 1
  for (int ti = 0; ti < 2; ++ti) {
    const int tt = ti ? pair : 15 - pair;
    const int t0 = tt * 128;
    const int Q = (tt + 1) * 2;
    f32x4 acc[2][4] = {};

    auto stage = [&](int q, int bufi) {
      const u16* Xblk = Xtile + (size_t)q * 4096;
#pragma unroll
      for (int i = 0; i < 2; ++i) {
        const int c = i * 256 + tid;
        const int row = c >> 3, cc = c & 7;
        load_lds16(Xblk + row * 64 + ((cc ^ (row & 7)) << 3),
                   &Xs[bufi][i * 2048 + wv * 512]);
      }
      const int st = q >> 1, k = q & 1;
      const u16* Ab = Vh + (size_t)(tt - st) * 128 * 128 + k * 64;
#pragma unroll
      for (int i = 0; i < 4; ++i) {
        const int c = i * 256 + tid;
        const int row = c >> 3, cc = c & 7;
        load_lds16(Ab + row * 128 + ((cc ^ (row & 7)) * 8),
                   &As[bufi][i * 2048 + wv * 512]);
      }
    };

    stage(0, 0);
    if (Q > 1) stage(1, 1);
    asm volatile("s_waitcnt vmcnt(6)" ::: "memory");
    __builtin_amdgcn_sched_barrier(0);
    __builtin_amdgcn_s_barrier();
    asm volatile("" ::: "memory");

    int cur = 0;
    for (int q = 0; q < Q; ++q) {
      if (q + 2 < Q) stage(q + 2, (q + 2) % 3);
#pragma unroll
      for (int ks = 0; ks < 2; ++ks) {
        bf16x8 af[2];
#pragma unroll
        for (int tf = 0; tf < 2; ++tf) {
          const int row = wv * 32 + tf * 16 + l15;
          af[tf] = *(const bf16x8*)(&As[cur][row * 64 + (((ks * 4 + g) ^ (row & 7)) * 8)]);
        }
        __builtin_amdgcn_s_setprio(1);
#pragma unroll
        for (int nf = 0; nf < 4; ++nf) {
          const int row = nf * 16 + l15;
          const bf16x8 bv = *(const bf16x8*)(&Xs[cur][row * 64 + (((ks * 4 + g) ^ (row & 7)) * 8)]);
#pragma unroll
          for (int tf = 0; tf < 2; ++tf)
            acc[tf][nf] = MF(af[tf], bv, acc[tf][nf]);
        }
        __builtin_amdgcn_s_setprio(0);
      }
      if (q + 2 < Q)      asm volatile("s_waitcnt vmcnt(6)" ::: "memory");
      else if (q + 1 < Q) asm volatile("s_waitcnt vmcnt(0)" ::: "memory");
      __builtin_amdgcn_sched_barrier(0);
      __builtin_amdgcn_s_barrier();
      asm volatile("" ::: "memory");
      cur = (cur == 2) ? 0 : cur + 1;
    }

    // Y2b in GEMM-tile layout: n = b*2048+t, ntile = b*16+tt, ktile = h, col = d
    u16* Yblk = Y2b + (size_t)((b * 16 + tt) * 16 + h) * 8192;
#pragma unroll
    for (int tf = 0; tf < 2; ++tf) {
#pragma unroll
      for (int r = 0; r < 4; ++r) {
        const int t = t0 + wv * 32 + tf * 16 + g * 4 + r;
        const int trow = wv * 32 + tf * 16 + g * 4 + r;   // t & 127
        const float inv = 1.0f / normB[h * 2048 + t];
        const float bb = biasB[h * 2048 + t];
#pragma unroll
        for (int nf = 0; nf < 4; ++nf) {
          const int d = nf * 16 + l15;
          Yblk[trow * 64 + d] = f2bf(acc[tf][nf][r] * inv + bb);
        }
      }
    }
  }
}

extern "C" void kernel_launch(void* const* d_in, const int* in_sizes, int n_in,
                              void* d_out, int out_size, void* d_ws, size_t ws_size,
                              hipStream_t stream) {
  (void)in_sizes; (void)n_in; (void)out_size; (void)ws_size;
  const float* x      = (const float*)d_in[0];
  const float* weight = (const float*)d_in[1];
  const float* biasB  = (const float*)d_in[2];
  const float* inp_w  = (const float*)d_in[3];
  const float* inp_b  = (const float*)d_in[4];
  const float* out_w  = (const float*)d_in[5];

  char* ws = (char*)d_ws;
  u16* Xb    = (u16*)(ws + 0);                         // x bf16 tiled  16 MB
  u16* X1t   = (u16*)(ws + (size_t)(16u << 20));       // x1 tiled      16 MB [h][b][stile][64][64]
  u16* Y2b   = (u16*)(ws + (size_t)(32u << 20));       // conv out tiled 16 MB
  u16* Wb    = (u16*)(ws + (size_t)(48u << 20));       // inp_w tiled    2 MB
  u16* OWb   = (u16*)(ws + (size_t)(50u << 20));       // out_w tiled    2 MB
  float* normB = (float*)(ws + (size_t)(53u << 20));   // cumsum       128 KB
  u16* Vt    = (u16*)(ws + (size_t)(56u << 20));       // Toeplitz V     8 MB

  // prep upstream of GEMM1 only (x + inp_w casts, tiled outputs)
  prep_pre<<<9216, 256, 0, stream>>>(x, inp_w, Xb, Wb);

  // GEMM1 (512 blocks, tiled operands + tiled C) + overlapped prep_post (1296 blocks)
  gemm_nt4<true, false, 0, true, true><<<1808, 256, 0, stream>>>(
      Wb, Xb, (void*)X1t, inp_b, 1024, 8192,
      out_w, weight, OWb, normB, Vt);

  // Y2b_tiled = (toeplitz conv of X1t_tiled) / norm + bias
  toep_conv<<<512, 256, 0, stream>>>(X1t, Vt, normB, biasB, Y2b);

  // out[(b,t)][e'] = sum_e Y2b[(b,t)][e] * out_w[e',e]  (tiled A/B, row-major f32 C)
  gemm_nt4<false, true, 1, false, false><<<512, 256, 0, stream>>>(
      Y2b, OWb, d_out, nullptr, 1024, 1024,
      nullptr, nullptr, nullptr, nullptr, nullptr);
}

// Round 28
// 93.178 us; speedup vs baseline: 1.0029x; 1.0029x over previous
//
#include <hip/hip_runtime.h>

typedef unsigned short u16;
typedef __attribute__((ext_vector_type(4))) float f32x4;
typedef __attribute__((ext_vector_type(8))) __bf16 bf16x8;

__device__ __forceinline__ u16 f2bf(float f) {
  unsigned u = __builtin_bit_cast(unsigned, f);
  u = u + 0x7fffu + ((u >> 16) & 1u);
  return (u16)(u >> 16);
}

__device__ __forceinline__ void load_lds16(const void* g, void* l) {
  __builtin_amdgcn_global_load_lds((__attribute__((address_space(1))) void*)g,
                                   (__attribute__((address_space(3))) void*)l,
                                   16, 0, 0);
}

__device__ __forceinline__ f32x4 MF(bf16x8 a, bf16x8 b, f32x4 c) {
  return __builtin_amdgcn_mfma_f32_16x16x32_bf16(a, b, c, 0, 0, 0);
}

// GEMM-tile layout: buf[(row>>7)*(K/64) + (col>>6)][row&127][col&63], 16KB tiles.
// Each GEMM K-stage then loads ONE contiguous block per operand (r26-proven mechanism).
__device__ __forceinline__ size_t gtile_off(int row, int col, int ktiles) {
  return (size_t)((row >> 7) * ktiles + (col >> 6)) * 8192 + (row & 127) * 64 + (col & 63);
}

// Upstream-of-GEMM1 preprocessing (outputs in GEMM-tile layout):
//  blocks    0..8191: cast x (f32 -> bf16) -> Xb tiled [8192 x 1024]
//  blocks 8192..9215: cast inp_w -> Wb tiled [1024 x 1024]
__global__ __launch_bounds__(256) void prep_pre(const float* __restrict__ x,
                                                const float* __restrict__ inp_w,
                                                u16* __restrict__ Xb,
                                                u16* __restrict__ Wb) {
  const int bx = blockIdx.x, tid = threadIdx.x;
  const float* src; u16* dst; int i;
  if (bx < 8192) { src = x;     dst = Xb; i = bx * 256 + tid; }
  else           { src = inp_w; dst = Wb; i = (bx - 8192) * 256 + tid; }
  const float4 v = ((const float4*)src)[i];
  ushort4 o;
  o.x = f2bf(v.x); o.y = f2bf(v.y); o.z = f2bf(v.z); o.w = f2bf(v.w);
  const int row = i >> 8, col = (i & 255) * 4;   // lda = 1024 for both
  *(ushort4*)(dst + gtile_off(row, col, 16)) = o;
}

// Prep branches not needed by GEMM1, run as extra blocks inside GEMM1's launch:
//  ex    0..1023: cast out_w -> OWb tiled
//  ex 1024..1039: per-head cumsum of weight -> normB
//  ex 1040..1295: build Toeplitz operand V[h][t'][j] = (t'>=j)?w[h][t'-j]:0
__device__ void prep_post_block(int ex, int tid,
                                const float* __restrict__ out_w,
                                const float* __restrict__ weight,
                                u16* __restrict__ OWb,
                                float* __restrict__ normB,
                                u16* __restrict__ V) {
  if (ex < 1024) {
    const int i = ex * 256 + tid;
    const float4 v = ((const float4*)out_w)[i];
    ushort4 o;
    o.x = f2bf(v.x); o.y = f2bf(v.y); o.z = f2bf(v.z); o.w = f2bf(v.w);
    const int row = i >> 8, col = (i & 255) * 4;
    *(ushort4*)(OWb + gtile_off(row, col, 16)) = o;
    return;
  }
  if (ex < 1040) {
    const int h = ex - 1024;
    __shared__ float ts[256];
    float v[8];
    const float* src = weight + h * 2048 + tid * 8;
    float s = 0.f;
#pragma unroll
    for (int j = 0; j < 8; ++j) v[j] = src[j];
#pragma unroll
    for (int j = 0; j < 8; ++j) { s += v[j]; v[j] = s; }
    ts[tid] = s;
    __syncthreads();
    float xx = s;
#pragma unroll
    for (int d = 1; d < 256; d <<= 1) {
      float y = (tid >= d) ? ts[tid - d] : 0.f;
      __syncthreads();
      xx += y;
      ts[tid] = xx;
      __syncthreads();
    }
    const float excl = xx - s;
    float* dst = normB + h * 2048 + tid * 8;
#pragma unroll
    for (int j = 0; j < 8; ++j) dst[j] = excl + v[j];
    return;
  }
  {
    const int bb = ex - 1040;
    const int h = bb & 15, tb = bb >> 4;
    __shared__ u16 wl[2048];
#pragma unroll
    for (int j = 0; j < 8; ++j) wl[tid * 8 + j] = f2bf(weight[h * 2048 + tid * 8 + j]);
    __syncthreads();
#pragma unroll
    for (int i = 0; i < 8; ++i) {
      const int cid = i * 256 + tid;
      const int row = cid >> 4, c = cid & 15;
      const int t = tb * 128 + row;
      const int j0 = c * 8;
      unsigned v[8];
#pragma unroll
      for (int jj = 0; jj < 8; ++jj) {
        const int j = j0 + jj;
        v[jj] = (t >= j) ? (unsigned)wl[t - j] : 0u;
      }
      uint4 o;
      o.x = v[0] | (v[1] << 16); o.y = v[2] | (v[3] << 16);
      o.z = v[4] | (v[5] << 16); o.w = v[6] | (v[7] << 16);
      *(uint4*)(V + ((size_t)(h * 2048 + t)) * 128 + j0) = o;
    }
  }
}

// NT GEMM, operands in GEMM-tile layout (each stage = 2 contiguous 16KB blocks).
// BM=BN=128, BK=64, 4 waves (2x2, 64x64/wave), 2-deep LDS dbuf (64KB -> 2 blocks/CU).
// DEC=0 (GEMM1): per-XCD 8m x 8n square chunk; blocks >= 512 run prep_post overlap;
//   TILEC: C written in toep-tiled layout [h][b][stile][64d][64s].
// DEC=1 (GEMM3): sw remap, row-major f32 C.
template <bool BIAS, bool F32OUT, int DEC, bool POST, bool TILEC>
__global__ __launch_bounds__(256) void gemm_nt4(const u16* __restrict__ A,
                                                const u16* __restrict__ B,
                                                void* __restrict__ C,
                                                const float* __restrict__ bias,
                                                int K, int ldc,
                                                const float* __restrict__ out_w,
                                                const float* __restrict__ weight,
                                                u16* __restrict__ OWb,
                                                float* __restrict__ normB,
                                                u16* __restrict__ Vt) {
  const int flatAll = (int)blockIdx.x;
  if (POST && flatAll >= 512) {
    prep_post_block(flatAll - 512, threadIdx.x, out_w, weight, OWb, normB, Vt);
    return;
  }
  __shared__ __align__(16) u16 As[2][128 * 64];
  __shared__ __align__(16) u16 Bs[2][128 * 64];
  const int tid = threadIdx.x;
  const int lane = tid & 63, wv = tid >> 6;
  const int wm = wv >> 1, wn = wv & 1;
  const int l15 = lane & 15, g = lane >> 4;

  const int flat = flatAll;
  int m0, n0;
  if (DEC == 0) {
    const int xcd = flat & 7, i = flat >> 3;
    m0 = (i & 7) * 128;
    n0 = ((xcd << 3) + (i >> 3)) * 128;
  } else {
    const int sw = (flat & 7) * 64 + (flat >> 3);
    m0 = (sw >> 3) * 128;
    n0 = (sw & 7) * 128;
  }

  const int NT = K >> 6;

  auto stage = [&](int t, int bi) {
    const u16* Ablk = A + (size_t)((m0 >> 7) * NT + t) * 8192;
#pragma unroll
    for (int i = 0; i < 4; ++i) {
      const int c = i * 256 + tid;
      const int row = c >> 3, cc = c & 7;
      load_lds16(Ablk + row * 64 + ((cc ^ (row & 7)) << 3),
                 &As[bi][i * 2048 + wv * 512]);
    }
    const u16* Bblk = B + (size_t)((n0 >> 7) * NT + t) * 8192;
#pragma unroll
    for (int i = 0; i < 4; ++i) {
      const int c = i * 256 + tid;
      const int row = c >> 3, cc = c & 7;
      load_lds16(Bblk + row * 64 + ((cc ^ (row & 7)) << 3),
                 &Bs[bi][i * 2048 + wv * 512]);
    }
  };

  f32x4 acc[4][4] = {};
  stage(0, 0);
  __syncthreads();
  int cur = 0;
  for (int t = 0; t < NT; ++t) {
    if (t + 1 < NT) stage(t + 1, cur ^ 1);
#pragma unroll
    for (int kh = 0; kh < 2; ++kh) {
      bf16x8 af[4], bf[4];
#pragma unroll
      for (int mf = 0; mf < 4; ++mf) {
        const int row = wm * 64 + mf * 16 + l15;
        af[mf] = *(const bf16x8*)(&As[cur][row * 64 + ((((kh << 2) + g) ^ (row & 7)) << 3)]);
      }
#pragma unroll
      for (int nf = 0; nf < 4; ++nf) {
        const int row = wn * 64 + nf * 16 + l15;
        bf[nf] = *(const bf16x8*)(&Bs[cur][row * 64 + ((((kh << 2) + g) ^ (row & 7)) << 3)]);
      }
      __builtin_amdgcn_s_setprio(1);
#pragma unroll
      for (int mf = 0; mf < 4; ++mf)
#pragma unroll
        for (int nf = 0; nf < 4; ++nf)
          acc[mf][nf] = MF(af[mf], bf[nf], acc[mf][nf]);
      __builtin_amdgcn_s_setprio(0);
    }
    __syncthreads();
    cur ^= 1;
  }

  // D layout (m89-verified): col = lane&15, row = (lane>>4)*4 + reg
#pragma unroll
  for (int mf = 0; mf < 4; ++mf) {
#pragma unroll
    for (int r = 0; r < 4; ++r) {
      const int row = m0 + wm * 64 + mf * 16 + g * 4 + r;
      const float bb = BIAS ? bias[row] : 0.f;
#pragma unroll
      for (int nf = 0; nf < 4; ++nf) {
        const int col = n0 + wn * 64 + nf * 16 + l15;
        const float v = acc[mf][nf][r] + bb;
        if (F32OUT) {
          ((float*)C)[(size_t)row * ldc + col] = v;
        } else if (TILEC) {
          // [h][b][stile][64d][64s]: h=row>>6, d=row&63, b=col>>11, stile=(col&2047)>>6
          const size_t off = (size_t)(row >> 6) * 524288 + (size_t)(col >> 11) * 131072 +
                             (size_t)((col & 2047) >> 6) * 4096 + (row & 63) * 64 + (col & 63);
          ((u16*)C)[off] = f2bf(v);
        } else {
          ((u16*)C)[(size_t)row * ldc + col] = f2bf(v);
        }
      }
    }
  }
}

// Causal Toeplitz conv (r10 structure + r21 micro-tweaks — best measured).
// X1t tiled [h][b][stile][64d][64s] (contiguous 8KB X-stages, r26-proven);
// Y2b written in GEMM-tile layout for GEMM3 (ktile = h exactly).
__global__ __launch_bounds__(256) void toep_conv(const u16* __restrict__ X1t,
                                                 const u16* __restrict__ V,
                                                 const float* __restrict__ normB,
                                                 const float* __restrict__ biasB,
                                                 u16* __restrict__ Y2b) {
  __shared__ __align__(16) u16 As[3][128 * 64];  // 3 x 16KB
  __shared__ __align__(16) u16 Xs[3][64 * 64];   // 3 x 8KB
  const int tid = threadIdx.x;
  const int lane = tid & 63, wv = tid >> 6;
  const int l15 = lane & 15, g = lane >> 4;

  const int x = (int)blockIdx.x;
  const int h = (x & 7) + 8 * ((x >> 3) & 1);   // xcd = wgid%8 -> h%8
  const int pb = x >> 4;                        // 0..31
  const int pair = pb & 7, b = pb >> 3;         // pair 0..7, b 0..3

  const u16* Vh = V + (size_t)h * 2048 * 128;
  const u16* Xtile = X1t + (size_t)h * 524288 + (size_t)b * 131072;

#pragma unroll 1
  for (int ti = 0; ti < 2; ++ti) {
    const int tt = ti ? pair : 15 - pair;
    const int t0 = tt * 128;
    const int Q = (tt + 1) * 2;
    f32x4 acc[2][4] = {};

    auto stage = [&](int q, int bufi) {
      const u16* Xblk = Xtile + (size_t)q * 4096;
#pragma unroll
      for (int i = 0; i < 2; ++i) {
        const int c = i * 256 + tid;
        const int row = c >> 3, cc = c & 7;
        load_lds16(Xblk + row * 64 + ((cc ^ (row & 7)) << 3),
                   &Xs[bufi][i * 2048 + wv * 512]);
      }
      const int st = q >> 1, k = q & 1;
      const u16* Ab = Vh + (size_t)(tt - st) * 128 * 128 + k * 64;
#pragma unroll
      for (int i = 0; i < 4; ++i) {
        const int c = i * 256 + tid;
        const int row = c >> 3, cc = c & 7;
        load_lds16(Ab + row * 128 + ((cc ^ (row & 7)) * 8),
                   &As[bufi][i * 2048 + wv * 512]);
      }
    };

    stage(0, 0);
    if (Q > 1) stage(1, 1);
    asm volatile("s_waitcnt vmcnt(6)" ::: "memory");
    __builtin_amdgcn_sched_barrier(0);
    __builtin_amdgcn_s_barrier();
    asm volatile("" ::: "memory");

    int cur = 0;
    for (int q = 0; q < Q; ++q) {
      if (q + 2 < Q) stage(q + 2, (q + 2) % 3);
#pragma unroll
      for (int ks = 0; ks < 2; ++ks) {
        bf16x8 af[2];
#pragma unroll
        for (int tf = 0; tf < 2; ++tf) {
          const int row = wv * 32 + tf * 16 + l15;
          af[tf] = *(const bf16x8*)(&As[cur][row * 64 + (((ks * 4 + g) ^ (row & 7)) * 8)]);
        }
        __builtin_amdgcn_s_setprio(1);
#pragma unroll
        for (int nf = 0; nf < 4; ++nf) {
          const int row = nf * 16 + l15;
          const bf16x8 bv = *(const bf16x8*)(&Xs[cur][row * 64 + (((ks * 4 + g) ^ (row & 7)) * 8)]);
#pragma unroll
          for (int tf = 0; tf < 2; ++tf)
            acc[tf][nf] = MF(af[tf], bv, acc[tf][nf]);
        }
        __builtin_amdgcn_s_setprio(0);
      }
      if (q + 2 < Q)      asm volatile("s_waitcnt vmcnt(6)" ::: "memory");
      else if (q + 1 < Q) asm volatile("s_waitcnt vmcnt(0)" ::: "memory");
      __builtin_amdgcn_sched_barrier(0);
      __builtin_amdgcn_s_barrier();
      asm volatile("" ::: "memory");
      cur = (cur == 2) ? 0 : cur + 1;
    }

    // Y2b in GEMM-tile layout: n = b*2048+t, ntile = b*16+tt, ktile = h, col = d
    u16* Yblk = Y2b + (size_t)((b * 16 + tt) * 16 + h) * 8192;
#pragma unroll
    for (int tf = 0; tf < 2; ++tf) {
#pragma unroll
      for (int r = 0; r < 4; ++r) {
        const int t = t0 + wv * 32 + tf * 16 + g * 4 + r;
        const int trow = wv * 32 + tf * 16 + g * 4 + r;   // t & 127
        const float inv = 1.0f / normB[h * 2048 + t];
        const float bb = biasB[h * 2048 + t];
#pragma unroll
        for (int nf = 0; nf < 4; ++nf) {
          const int d = nf * 16 + l15;
          Yblk[trow * 64 + d] = f2bf(acc[tf][nf][r] * inv + bb);
        }
      }
    }
  }
}

extern "C" void kernel_launch(void* const* d_in, const int* in_sizes, int n_in,
                              void* d_out, int out_size, void* d_ws, size_t ws_size,
                              hipStream_t stream) {
  (void)in_sizes; (void)n_in; (void)out_size; (void)ws_size;
  const float* x      = (const float*)d_in[0];
  const float* weight = (const float*)d_in[1];
  const float* biasB  = (const float*)d_in[2];
  const float* inp_w  = (const float*)d_in[3];
  const float* inp_b  = (const float*)d_in[4];
  const float* out_w  = (const float*)d_in[5];

  char* ws = (char*)d_ws;
  u16* Xb    = (u16*)(ws + 0);                         // x bf16 tiled  16 MB
  u16* X1t   = (u16*)(ws + (size_t)(16u << 20));       // x1 tiled      16 MB [h][b][stile][64][64]
  u16* Y2b   = (u16*)(ws + (size_t)(32u << 20));       // conv out tiled 16 MB
  u16* Wb    = (u16*)(ws + (size_t)(48u << 20));       // inp_w tiled    2 MB
  u16* OWb   = (u16*)(ws + (size_t)(50u << 20));       // out_w tiled    2 MB
  float* normB = (float*)(ws + (size_t)(53u << 20));   // cumsum       128 KB
  u16* Vt    = (u16*)(ws + (size_t)(56u << 20));       // Toeplitz V     8 MB

  // prep upstream of GEMM1 only (x + inp_w casts, tiled outputs)
  prep_pre<<<9216, 256, 0, stream>>>(x, inp_w, Xb, Wb);

  // GEMM1 (512 blocks, tiled operands + tiled C) + overlapped prep_post (1296 blocks)
  gemm_nt4<true, false, 0, true, true><<<1808, 256, 0, stream>>>(
      Wb, Xb, (void*)X1t, inp_b, 1024, 8192,
      out_w, weight, OWb, normB, Vt);

  // Y2b_tiled = (toeplitz conv of X1t_tiled) / norm + bias
  toep_conv<<<512, 256, 0, stream>>>(X1t, Vt, normB, biasB, Y2b);

  // out[(b,t)][e'] = sum_e Y2b[(b,t)][e] * out_w[e',e]  (tiled A/B, row-major f32 C)
  gemm_nt4<false, true, 1, false, false><<<512, 256, 0, stream>>>(
      Y2b, OWb, d_out, nullptr, 1024, 1024,
      nullptr, nullptr, nullptr, nullptr, nullptr);
}